// Round 7
// baseline (409.265 us; speedup 1.0000x reference)
//
#include <hip/hip_runtime.h>
#include <hip/hip_bf16.h>

#define SEQ 1024
#define NH  16

typedef __attribute__((ext_vector_type(8))) short short8;
typedef __attribute__((ext_vector_type(4))) float floatx4;
typedef __attribute__((ext_vector_type(4))) unsigned short ushortx4;

// async global->LDS, 16B per lane; LDS dest = wave-uniform base + lane*16
#define GLDS16(gp, lp) __builtin_amdgcn_global_load_lds( \
    (const __attribute__((address_space(1))) void*)(gp), \
    (__attribute__((address_space(3))) void*)(lp), 16, 0, 0)

__device__ __forceinline__ unsigned short f2b(float f) {   // fp32 -> bf16 RNE
    union { float f; unsigned u; } v; v.f = f;
    unsigned r = (v.u + 0x7fffu + ((v.u >> 16) & 1u)) >> 16;
    return (unsigned short)r;
}
__device__ __forceinline__ float b2f(unsigned short h) {
    union { unsigned u; float f; } v; v.u = ((unsigned)h) << 16;
    return v.f;
}

// swizzled addr (elem offsets) in a 64-wide bf16 tile: 8 chunks of 8 elems/row
#define TADDR(base, row, ch) ((base) + ((row) << 6) + ((((ch) ^ ((row) & 7))) << 3))
// U/W slab [16 ll][64 x], 4-elem chunk XOR swizzle (stride 64, no pad)
#define UWA(base, ll, x) ((base) + ((ll) << 6) + (((((x) >> 2) ^ (ll)) & 15) << 2) + ((x) & 3))

// ---------------- k0: fp32 -> bf16 casts ----------------
__global__ void cast_kernel(const float* __restrict__ hs, const float* __restrict__ W,
                            const float* __restrict__ E,
                            unsigned short* __restrict__ hsb,
                            unsigned short* __restrict__ Wb,
                            unsigned short* __restrict__ Eb)
{
    const int QH = 1048576, QW = 786432, QE = 32752;   // quads
    const int NT = QH + QW + QE;
    for (int q = blockIdx.x * 256 + threadIdx.x; q < NT; q += gridDim.x * 256) {
        const float* src; unsigned short* dst; int off;
        if (q < QH)           { src = hs; dst = hsb; off = q; }
        else if (q < QH + QW) { src = W;  dst = Wb;  off = q - QH; }
        else                  { src = E;  dst = Eb;  off = q - QH - QW; }
        const float4 v = *(const float4*)(src + (size_t)off * 4);
        ushortx4 o; o[0] = f2b(v.x); o[1] = f2b(v.y); o[2] = f2b(v.z); o[3] = f2b(v.w);
        *(ushortx4*)(dst + (size_t)off * 4) = o;
    }
}

// ---------------- k1: QKV projection, bf16 MFMA, dbuf K-loop ----------------
// LDS 32 KB: two 16 KB buffers (A 8 KB + B 8 KB each); reused by epilogue transpose.
__global__ __launch_bounds__(256, 3) void qkv_gemm(
    const unsigned short* __restrict__ Ab, const unsigned short* __restrict__ Bb,
    const float* __restrict__ bias,
    unsigned short* __restrict__ Qb, unsigned short* __restrict__ Kb,
    unsigned short* __restrict__ Vt)
{
    __shared__ unsigned short sm[16384];
    const int t = threadIdx.x, w = t >> 6;
    const int ln = t & 15, g = (t >> 4) & 3;
    const int wm = w >> 1, wn = w & 1;
    const int m0 = blockIdx.y << 7, o0 = blockIdx.x << 7;

    floatx4 acc[4][4];
#pragma unroll
    for (int i = 0; i < 4; ++i)
#pragma unroll
        for (int j = 0; j < 4; ++j) acc[i][j] = (floatx4){0.f, 0.f, 0.f, 0.f};

    auto stage = [&](int kb, int p) {
#pragma unroll
        for (int piece = 0; piece < 2; ++piece) {
            const int idx = (piece << 8) + t;
            const int row = idx >> 2;
            const int c = (idx & 3) ^ ((row ^ (row >> 2)) & 3);
            GLDS16(Ab + (size_t)(m0 + row) * 1024 + kb + (c << 3),
                   (char*)sm + (p << 14) + (piece << 12) + (w << 10));
            GLDS16(Bb + (size_t)(o0 + row) * 1024 + kb + (c << 3),
                   (char*)sm + (p << 14) + 8192 + (piece << 12) + (w << 10));
        }
    };

    stage(0, 0);
#pragma unroll 1
    for (int it = 0; it < 32; ++it) {
        const int p = it & 1;
        __syncthreads();                      // staged(it) visible; prev reads done
        if (it < 31) stage((it + 1) << 5, p ^ 1);
        const int pe = p << 13;               // elem base of buffer p
        short8 af[4], bf_[4];
#pragma unroll
        for (int i = 0; i < 4; ++i) {
            const int r = (wm << 6) + (i << 4) + ln;
            af[i] = *(const short8*)&sm[pe + (r << 5) + ((g ^ ((r ^ (r >> 2)) & 3)) << 3)];
        }
#pragma unroll
        for (int j = 0; j < 4; ++j) {
            const int r = (wn << 6) + (j << 4) + ln;
            bf_[j] = *(const short8*)&sm[pe + 4096 + (r << 5) + ((g ^ ((r ^ (r >> 2)) & 3)) << 3)];
        }
#pragma unroll
        for (int i = 0; i < 4; ++i)
#pragma unroll
            for (int j = 0; j < 4; ++j)
                acc[i][j] = __builtin_amdgcn_mfma_f32_16x16x32_bf16(af[i], bf_[j], acc[i][j], 0, 0, 0);
    }
    __syncthreads();                          // K-loop reads done; reuse sm

    const int which = o0 >> 10;     // 0=Q 1=K 2=V (block-uniform)
    float bj[4];
#pragma unroll
    for (int j = 0; j < 4; ++j) bj[j] = bias[o0 + (wn << 6) + (j << 4) + ln];

    if (which == 2) {
        // V: LDS as [ol][ml] (o-major) -> b128 rows = 8 consecutive s -> coalesced Vt stores
#pragma unroll
        for (int i = 0; i < 4; ++i)
#pragma unroll
            for (int q = 0; q < 4; ++q) {
                const int ml = (wm << 6) + (i << 4) + (g << 2) + q;
#pragma unroll
                for (int j = 0; j < 4; ++j) {
                    const int ol = (wn << 6) + (j << 4) + ln;
                    sm[(ol << 7) + ((((ml >> 3) ^ (ol & 15))) << 3) + (ml & 7)] =
                        f2b(acc[i][j][q] + bj[j]);
                }
            }
        __syncthreads();
        const int b = m0 >> 10;
#pragma unroll
        for (int rr = 0; rr < 8; ++rr) {
            const int orow = (rr << 4) + (t >> 4);
            const int c = t & 15;
            const short8 v = *(const short8*)&sm[(orow << 7) + ((c ^ (orow & 15)) << 3)];
            const int o = o0 + orow, hh = (o >> 6) & 15, d = o & 63;
            const int s = (m0 & 1023) + (c << 3);
            *(short8*)(Vt + (((size_t)((b << 4) + hh)) << 16) + (d << 10) + s) = v;
        }
    } else {
        // Q/K: LDS as [ml][ol] -> b128 rows -> coalesced row stores
        unsigned short* dst = which ? Kb : Qb;
        const float sc = which ? 1.0f : 0.125f;   // fold 1/sqrt(64) into Q
#pragma unroll
        for (int i = 0; i < 4; ++i)
#pragma unroll
            for (int q = 0; q < 4; ++q) {
                const int ml = (wm << 6) + (i << 4) + (g << 2) + q;
#pragma unroll
                for (int j = 0; j < 4; ++j) {
                    const int ol = (wn << 6) + (j << 4) + ln;
                    sm[(ml << 7) + ((((ol >> 3) ^ (ml & 15))) << 3) + (ol & 7)] =
                        f2b((acc[i][j][q] + bj[j]) * sc);
                }
            }
        __syncthreads();
#pragma unroll
        for (int rr = 0; rr < 8; ++rr) {
            const int row = (rr << 4) + (t >> 4);
            const int c = t & 15;
            const short8 v = *(const short8*)&sm[(row << 7) + ((c ^ (row & 15)) << 3)];
            const int m = m0 + row, b = m >> 10, s = m & 1023;
            const int o = o0 + (c << 3), hh = (o >> 6) & 15, d = o & 63;
            *(short8*)(dst + (((size_t)((b << 4) + hh)) << 16) + (s << 6) + d) = v;
        }
    }
}

// ---------------- k2: flash attention, transposed-S dataflow (r6) + LDS diet ----------------
// LDS elems (40960 B total, 4 blocks/CU): Kbuf dbuf [0,8192) (P overlays Kbuf[cur]),
//   V [8192,12288), U slabs [12288,16384), W slabs [16384,20480)
// 3 barriers/iter; E fragments from global (L2-hot).
__global__ __launch_bounds__(256, 4) void attn_mfma(
    const unsigned short* __restrict__ Qb, const unsigned short* __restrict__ Kb,
    const unsigned short* __restrict__ Vt, const unsigned short* __restrict__ Eb,
    const float* __restrict__ mask, float* __restrict__ outp)
{
    __shared__ unsigned short sm[20480];
    const int t = threadIdx.x, w = t >> 6;
    const int ln = t & 15, g = (t >> 4) & 3;
    const int bh = blockIdx.x >> 4;
    const int l0 = (blockIdx.x & 15) << 6;
    const int b = bh >> 4, h = bh & 15;
    const size_t hb = (size_t)bh << 16;

    const int VB = 8192;
    const int us  = 12288 + (w << 10);     // this wave's U slab [ll][t], swizzled
    const int wsb = 16384 + (w << 10);     // this wave's W slab [ll][r], swizzled

    // Q B-frag (own l-group only), loop-invariant, pre-scaled bf16
    short8 qa0, qa1;
    {
        const unsigned short* qp = Qb + hb + ((size_t)(l0 + (w << 4) + ln) << 6) + (g << 3);
        qa0 = *(const short8*)qp;
        qa1 = *(const short8*)(qp + 32);
    }

    // prologue: stage K(0) -> Kbuf[0]
#pragma unroll
    for (int p = 0; p < 2; ++p) {
        const int idx = (p << 8) + t, row = idx >> 3, c = (idx & 7) ^ (row & 7);
        GLDS16(Kb + hb + ((size_t)row << 6) + (c << 3),
               (char*)sm + (p << 12) + (w << 10));
    }
    __syncthreads();

    floatx4 O[4];
#pragma unroll
    for (int dt = 0; dt < 4; ++dt) O[dt] = (floatx4){0.f, 0.f, 0.f, 0.f};
    float lr = 0.f;

#pragma unroll 1
    for (int r0 = 0; r0 < SEQ; r0 += 64) {
        const int cur = (r0 >> 6) & 1, nxt = cur ^ 1;
        __syncthreads();                         // A: prev PV (P,V) reads retired
        // stage K(r0+64) -> Kbuf[nxt], V(r0) -> VB (both visible at C)
#pragma unroll
        for (int p = 0; p < 2; ++p) {
            const int idx = (p << 8) + t, row = idx >> 3, c = (idx & 7) ^ (row & 7);
            GLDS16(Kb + hb + ((size_t)(r0 + 64 + row) << 6) + (c << 3),
                   (char*)sm + (nxt << 13) + (p << 12) + (w << 10));
            GLDS16(Vt + hb + ((size_t)row << 10) + r0 + (c << 3),
                   (char*)sm + 16384 + (p << 12) + (w << 10));
        }

        // E band fragments from global: 5 x 16-row slabs, wave-specific
        const int j0w = l0 + (w << 4) - r0 + 960;
        short8 ef[5][2];
#pragma unroll
        for (int dg = 0; dg < 5; ++dg) {
            const unsigned short* ep = Eb + ((size_t)(j0w + (dg << 4) + ln) << 6) + (g << 3);
            ef[dg][0] = *(const short8*)ep;
            ef[dg][1] = *(const short8*)(ep + 32);
        }
        // kf from Kbuf[cur] (staged last iter, visible since C(prev))
        short8 kf[4][2];
        const int kb0 = cur << 12;
#pragma unroll
        for (int j = 0; j < 4; ++j) {
            const int kr = (j << 4) + ln;
            kf[j][0] = *(const short8*)&sm[TADDR(kb0, kr, g)];
            kf[j][1] = *(const short8*)&sm[TADDR(kb0, kr, 4 + g)];
        }
        // S^T = K Q^T : lane holds S[r = 16j+4g+reg][l = 16w+ln]
        floatx4 S[4];
#pragma unroll
        for (int j = 0; j < 4; ++j) {
            floatx4 z = (floatx4){0.f, 0.f, 0.f, 0.f};
            z = __builtin_amdgcn_mfma_f32_16x16x32_bf16(kf[j][0], qa0, z, 0, 0, 0);
            S[j] = __builtin_amdgcn_mfma_f32_16x16x32_bf16(kf[j][1], qa1, z, 0, 0, 0);
        }
        // U = Q E^T over the 5-slab band; triangular merge dg0/dg4
        floatx4 Uo[5];
#pragma unroll
        for (int dg = 0; dg < 5; ++dg) {
            floatx4 z = (floatx4){0.f, 0.f, 0.f, 0.f};
            z = __builtin_amdgcn_mfma_f32_16x16x32_bf16(qa0, ef[dg][0], z, 0, 0, 0);
            Uo[dg] = __builtin_amdgcn_mfma_f32_16x16x32_bf16(qa1, ef[dg][1], z, 0, 0, 0);
        }
#pragma unroll
        for (int reg = 0; reg < 4; ++reg) {
            const int ll = (g << 2) + reg;
            const int tm = ln - ll;              // in [-15,15]
            const float v04 = (tm >= 0) ? Uo[0][reg] : Uo[4][reg];
            sm[UWA(us, ll, (tm & 63))] = f2b(v04);
            sm[UWA(us, ll, (16 + tm))] = f2b(Uo[1][reg]);
            sm[UWA(us, ll, (32 + tm))] = f2b(Uo[2][reg]);
            sm[UWA(us, ll, (48 + tm))] = f2b(Uo[3][reg]);
        }
        // W = K E^T; complementary slab pair (3-j, 4-j) merged per element
#pragma unroll
        for (int j = 0; j < 4; ++j) {
            floatx4 zlo = (floatx4){0.f, 0.f, 0.f, 0.f};
            floatx4 zhi = (floatx4){0.f, 0.f, 0.f, 0.f};
            zlo = __builtin_amdgcn_mfma_f32_16x16x32_bf16(kf[j][0], ef[3 - j][0], zlo, 0, 0, 0);
            zlo = __builtin_amdgcn_mfma_f32_16x16x32_bf16(kf[j][1], ef[3 - j][1], zlo, 0, 0, 0);
            zhi = __builtin_amdgcn_mfma_f32_16x16x32_bf16(kf[j][0], ef[4 - j][0], zhi, 0, 0, 0);
            zhi = __builtin_amdgcn_mfma_f32_16x16x32_bf16(kf[j][1], ef[4 - j][1], zhi, 0, 0, 0);
#pragma unroll
            for (int reg = 0; reg < 4; ++reg) {
                const int x = ln + (g << 2) + reg;          // in [0,30]
                const float v = (x >= 15) ? zlo[reg] : zhi[reg];
                const int ll = (x + 1) & 15;
                sm[UWA(wsb, ll, ((j << 4) + (g << 2) + reg))] = f2b(v * 0.125f);
            }
        }
        __syncthreads();                         // C: U/W + V + Kbuf[nxt] visible

        // scores + exp + P (vector LDS ops); P overlays Kbuf[cur] (kf reads done pre-C)
        float ts = 0.f;
        const int l = (w << 4) + ln;
        const int PB = cur << 12;
#pragma unroll
        for (int j = 0; j < 4; ++j) {
            const float4 mk = *(const float4*)(mask + (b << 10) + r0 + (j << 4) + (g << 2));
            const int rb = (j << 4) + (g << 2);
            const int t0 = 60 - rb;
            const ushortx4 u4 = *(const ushortx4*)&sm[UWA(us, ln, t0)];
            const ushortx4 w4 = *(const ushortx4*)&sm[UWA(wsb, ln, rb)];
            float e0 = __expf(S[j][0] + b2f(u4[3]) + b2f(w4[0]) + mk.x);
            float e1 = __expf(S[j][1] + b2f(u4[2]) + b2f(w4[1]) + mk.y);
            float e2 = __expf(S[j][2] + b2f(u4[1]) + b2f(w4[2]) + mk.z);
            float e3 = __expf(S[j][3] + b2f(u4[0]) + b2f(w4[3]) + mk.w);
            ts += (e0 + e1) + (e2 + e3);
            ushortx4 pk;
            pk[0] = f2b(e0); pk[1] = f2b(e1); pk[2] = f2b(e2); pk[3] = f2b(e3);
            *(ushortx4*)&sm[PB + (l << 6) + ((((rb >> 3) ^ (l & 7)) << 3)) + (rb & 7)] = pk;
        }
        lr += ts;
        __syncthreads();                         // D: P visible

        // PV: O^T[d][l] = V^T P^T ; A = V^T rows d, B = P rows l
        const short8 pa0 = *(const short8*)&sm[PB + (l << 6) + ((g ^ (l & 7)) << 3)];
        const short8 pa1 = *(const short8*)&sm[PB + (l << 6) + (((4 + g) ^ (l & 7)) << 3)];
#pragma unroll
        for (int dt = 0; dt < 4; ++dt) {
            const int vr = (dt << 4) + ln;
            const short8 v0 = *(const short8*)&sm[TADDR(VB, vr, g)];
            const short8 v1 = *(const short8*)&sm[TADDR(VB, vr, 4 + g)];
            O[dt] = __builtin_amdgcn_mfma_f32_16x16x32_bf16(v0, pa0, O[dt], 0, 0, 0);
            O[dt] = __builtin_amdgcn_mfma_f32_16x16x32_bf16(v1, pa1, O[dt], 0, 0, 0);
        }
    }

    // denominator: lanes sharing l differ in bits 4,5 of tid
    float s = lr;
    s += __shfl_xor(s, 16);
    s += __shfl_xor(s, 32);
    const float inv = 1.f / s;
#pragma unroll
    for (int dt = 0; dt < 4; ++dt) {
        float4 o;
        o.x = O[dt][0] * inv; o.y = O[dt][1] * inv;
        o.z = O[dt][2] * inv; o.w = O[dt][3] * inv;
        *(float4*)(outp + ((size_t)b << 20) + ((size_t)(l0 + (w << 4) + ln) << 10)
                   + (h << 6) + (dt << 4) + (g << 2)) = o;
    }
}

extern "C" void kernel_launch(void* const* d_in, const int* in_sizes, int n_in,
                              void* d_out, int out_size, void* d_ws, size_t ws_size,
                              hipStream_t stream)
{
    const float* hs   = (const float*)d_in[0];   // [4,1024,1024]
    const float* qkvw = (const float*)d_in[1];   // [3072,1024]
    const float* qkvb = (const float*)d_in[2];   // [3072]
    const float* demb = (const float*)d_in[3];   // [2047,64]
    const float* mask = (const float*)d_in[4];   // [4,1,1,1024]
    float* out = (float*)d_out;

    char* ws = (char*)d_ws;
    unsigned short* hsb = (unsigned short*)(ws);              // 8,388,608 B
    unsigned short* Wb  = (unsigned short*)(ws + 8388608);    // 6,291,456 B
    unsigned short* Eb  = (unsigned short*)(ws + 14680064);   //   262,016 B
    unsigned short* Qb  = (unsigned short*)(ws + 14942208);   // 8,388,608 B (pre-scaled)
    unsigned short* Kb  = (unsigned short*)(ws + 23330816);   // 8,388,608 B
    unsigned short* Vt  = (unsigned short*)(ws + 31719424);   // 8,388,608 B (transposed)

    cast_kernel<<<2048, 256, 0, stream>>>(hs, qkvw, demb, hsb, Wb, Eb);
    qkv_gemm<<<dim3(24, 32), 256, 0, stream>>>(hsb, Wb, qkvb, Qb, Kb, Vt);
    attn_mfma<<<1024, 256, 0, stream>>>(Qb, Kb, Vt, Eb, mask, out);
}